// Round 4
// baseline (594.174 us; speedup 1.0000x reference)
//
#include <hip/hip_runtime.h>
#include <hip/hip_fp16.h>

// Problem constants (fixed by the reference)
#define NG    4096        // graphs
#define NPG   198         // nodes per graph
#define EPG   1584        // edges per graph
#define ETOT  (NG * EPG)  // total edges
#define GPB   8           // graphs per MLP block

// Workspace layout (floats):
#define HT_FLOATS (NG / GPB * 396 * GPB)
#define WT0_OFF   (HT_FLOATS)
#define WT1_OFF   (WT0_OFF + 396 * 200)
#define WT2_OFF   (WT1_OFF + 200 * 100)
#define WT3_OFF   (WT2_OFF + 100 * 50)
#define WT4_OFF   (WT3_OFF + 50 * 10)

#define BC2(u) __builtin_bit_cast(__half2, (u))

// ---------------------------------------------------------------------------
// Weight transpose for MLP: WT[k*M+o] = W[o*K+k]
// ---------------------------------------------------------------------------
__global__ __launch_bounds__(256) void wtrans_kernel(
    const float* __restrict__ w0, const float* __restrict__ w1,
    const float* __restrict__ w2, const float* __restrict__ w3,
    const float* __restrict__ w4, float* __restrict__ ws)
{
    const int b = blockIdx.x;
    const float* w; float* t; int K, M, nelem, base;
    if      (b < 310) { w = w0; t = ws + WT0_OFF; K = 396; M = 200; nelem = 79200; base = 0;   }
    else if (b < 389) { w = w1; t = ws + WT1_OFF; K = 200; M = 100; nelem = 20000; base = 310; }
    else if (b < 409) { w = w2; t = ws + WT2_OFF; K = 100; M = 50;  nelem = 5000;  base = 389; }
    else if (b < 411) { w = w3; t = ws + WT3_OFF; K = 50;  M = 10;  nelem = 500;   base = 409; }
    else              { w = w4; t = ws + WT4_OFF; K = 10;  M = 2;   nelem = 20;    base = 411; }
    const int e = (b - base) * 256 + threadIdx.x;
    if (e < nelem) {
        const int o = e / K, k = e - o * K;
        t[k * M + o] = w[e];
    }
}

// ---------------------------------------------------------------------------
// Conv: edge-parallel gather with segmented reduction.
// ---------------------------------------------------------------------------

template <int AGGW>
__device__ __forceinline__ void zero_agg(float* __restrict__ agg, int tid)
{
    constexpr int NQ = (NPG * AGGW) / 4;
    const float4 z = make_float4(0.f, 0.f, 0.f, 0.f);
    for (int i = tid; i < NQ; i += 256)
        ((float4*)agg)[i] = z;
}

template <int CIN, int RINW, int AGGW>
__device__ __forceinline__ void gather(
    const unsigned* __restrict__ fbuf, float* __restrict__ agg,
    const unsigned ereg[7], int ecnt)
{
    constexpr int MS = (CIN + 1) / 2;
    __half2 ms[MS];
#pragma unroll
    for (int p = 0; p < MS; ++p) ms[p] = __floats2half2_rn(0.f, 0.f);

#pragma unroll
    for (int i = 0; i < 7; ++i) {
        if (i < ecnt) {
            const unsigned e  = ereg[i];
            const unsigned dl = (e >> 8) & 255u;
            const __half2  w2 = BC2((e >> 16) * 0x10001u);
            const unsigned* row = fbuf + (e & 255u) * RINW;
            if constexpr (RINW == 1) {
                ms[0] = __hfma2(w2, BC2(row[0]), ms[0]);
            } else if constexpr (RINW == 4) {
                const uint4 q = *(const uint4*)row;
                ms[0] = __hfma2(w2, BC2(q.x), ms[0]);
                ms[1] = __hfma2(w2, BC2(q.y), ms[1]);
                ms[2] = __hfma2(w2, BC2(q.z), ms[2]);
            } else if constexpr (RINW == 8) {
                const uint4 q0 = *(const uint4*)row;
                const uint4 q1 = *(const uint4*)(row + 4);
                ms[0] = __hfma2(w2, BC2(q0.x), ms[0]);
                ms[1] = __hfma2(w2, BC2(q0.y), ms[1]);
                ms[2] = __hfma2(w2, BC2(q0.z), ms[2]);
                ms[3] = __hfma2(w2, BC2(q0.w), ms[3]);
                ms[4] = __hfma2(w2, BC2(q1.x), ms[4]);
                if constexpr (MS > 5) {
                    ms[5] = __hfma2(w2, BC2(q1.y), ms[5]);
                    ms[6] = __hfma2(w2, BC2(q1.z), ms[6]);
                    ms[7] = __hfma2(w2, BC2(q1.w), ms[7]);
                }
            } else { // RINW == 12, CIN == 20
                const uint4 q0 = *(const uint4*)row;
                const uint4 q1 = *(const uint4*)(row + 4);
                const uint4 q2 = *(const uint4*)(row + 8);
                ms[0] = __hfma2(w2, BC2(q0.x), ms[0]);
                ms[1] = __hfma2(w2, BC2(q0.y), ms[1]);
                ms[2] = __hfma2(w2, BC2(q0.z), ms[2]);
                ms[3] = __hfma2(w2, BC2(q0.w), ms[3]);
                ms[4] = __hfma2(w2, BC2(q1.x), ms[4]);
                ms[5] = __hfma2(w2, BC2(q1.y), ms[5]);
                ms[6] = __hfma2(w2, BC2(q1.z), ms[6]);
                ms[7] = __hfma2(w2, BC2(q1.w), ms[7]);
                ms[8] = __hfma2(w2, BC2(q2.x), ms[8]);
                ms[9] = __hfma2(w2, BC2(q2.y), ms[9]);
            }
            const bool fl = (i + 1 >= ecnt) || (((ereg[i + 1] >> 8) & 255u) != dl);
            if (fl) {
                float* ar = agg + dl * AGGW;
#pragma unroll
                for (int p = 0; p < MS; ++p) {
                    const float2 f = __half22float2(ms[p]);
                    atomicAdd(ar + 2 * p, f.x);
                    if (2 * p + 1 < CIN) atomicAdd(ar + 2 * p + 1, f.y);
                    ms[p] = __floats2half2_rn(0.f, 0.f);
                }
            }
        }
    }
}

template <int CIN, int COUT, int AGGW, int RINW, int ROUTW>
__device__ __forceinline__ void dense(
    const float* __restrict__ agg, const unsigned* __restrict__ fin,
    unsigned* __restrict__ fout,
    const float* __restrict__ wrel, const float* __restrict__ brel,
    const float* __restrict__ wroot, int tid)
{
    if (tid >= NPG) return;

    float av[AGGW];
    if constexpr (AGGW == 2) {
        const float2 v = *(const float2*)(agg + tid * 2);
        av[0] = v.x; av[1] = v.y;
    } else {
#pragma unroll
        for (int qn = 0; qn < AGGW / 4; ++qn) {
            const float4 v = ((const float4*)(agg + tid * AGGW))[qn];
            av[4*qn] = v.x; av[4*qn+1] = v.y; av[4*qn+2] = v.z; av[4*qn+3] = v.w;
        }
    }

    float hv[CIN];
    const unsigned* srow = fin + tid * RINW;
    if constexpr (RINW == 1) {
        const float2 f = __half22float2(BC2(srow[0]));
        hv[0] = f.x; if constexpr (CIN > 1) hv[1] = f.y;
    } else {
#pragma unroll
        for (int qn = 0; qn < RINW / 4; ++qn) {
            const uint4 q = ((const uint4*)srow)[qn];
            const unsigned wd[4] = {q.x, q.y, q.z, q.w};
#pragma unroll
            for (int cc = 0; cc < 4; ++cc) {
                const int w = 4 * qn + cc;
                if (2 * w < CIN) {
                    const float2 f = __half22float2(BC2(wd[cc]));
                    hv[2 * w] = f.x;
                    if (2 * w + 1 < CIN) hv[2 * w + 1] = f.y;
                }
            }
        }
    }

    float outv[COUT];
#pragma unroll
    for (int o = 0; o < COUT; ++o) {
        float acc = brel[o];
#pragma unroll
        for (int c = 0; c < CIN; ++c) {
            acc = fmaf(av[c], wrel[o * CIN + c], acc);
            acc = fmaf(hv[c], wroot[o * CIN + c], acc);
        }
        outv[o] = fmaxf(acc, 0.f);
    }

    unsigned ow[ROUTW];
#pragma unroll
    for (int p = 0; p < ROUTW; ++p) {
        const float lo = (2*p     < COUT) ? outv[2*p]     : 0.f;
        const float hi = (2*p + 1 < COUT) ? outv[2*p + 1] : 0.f;
        ow[p] = __builtin_bit_cast(unsigned, __floats2half2_rn(lo, hi));
    }
    unsigned* orow = fout + tid * ROUTW;
    if constexpr (ROUTW == 1) {
        orow[0] = ow[0];
    } else if constexpr (ROUTW == 4) {
        *(uint4*)orow = make_uint4(ow[0], ow[1], ow[2], ow[3]);
    } else if constexpr (ROUTW == 8) {
        *(uint4*)orow       = make_uint4(ow[0], ow[1], ow[2], ow[3]);
        *(uint4*)(orow + 4) = make_uint4(ow[4], ow[5], ow[6], ow[7]);
    } else { // 12
        *(uint4*)orow       = make_uint4(ow[0], ow[1], ow[2], ow[3]);
        *(uint4*)(orow + 4) = make_uint4(ow[4], ow[5], ow[6], ow[7]);
        *(uint4*)(orow + 8) = make_uint4(ow[8], ow[9], ow[10], ow[11]);
    }
}

__global__ __launch_bounds__(256) void conv_kernel(
    const float* __restrict__ x,
    const int*   __restrict__ eidx,
    const float* __restrict__ ew,
    const float* wr0, const float* br0, const float* wq0,
    const float* wr1, const float* br1, const float* wq1,
    const float* wr2, const float* br2, const float* wq2,
    const float* wr3, const float* br3, const float* wq3,
    const float* wr4, const float* br4, const float* wq4,
    float* __restrict__ HT)
{
    // Union region: s_edge[1584] u32 | cursor[256] | cnt[256] | wsum[4]  then
    // reused as f32 agg buffer (max 198*20*4 = 15840 B).
    __shared__ __align__(16) unsigned char Ubytes[15840];
    __shared__ __align__(16) unsigned bufA[NPG * 8];   // x(1) / A2(8) / A4(4)
    __shared__ __align__(16) unsigned bufB[NPG * 12];  // A1(12) / A3(8) / A5(1)

    float*    aggF   = (float*)Ubytes;
    unsigned* s_edge = (unsigned*)Ubytes;              // [1584]
    unsigned* cursor = (unsigned*)(Ubytes + 6336);     // [256]
    unsigned* cnt    = (unsigned*)(Ubytes + 7360);     // [256]
    unsigned* wsum   = (unsigned*)(Ubytes + 8384);     // [4]

    const int g = blockIdx.x, tid = threadIdx.x;
    const int ebase = g * EPG, nbase = g * NPG;
    const int lane = tid & 63, wid = tid >> 6;

    // --- load all edges once into registers (quads) -------------------------
    const int4*   s4 = (const int4*)(eidx + ebase);
    const int4*   d4 = (const int4*)(eidx + ETOT + ebase);
    const float4* w4 = (const float4*)(ew + ebase);
    const int4   sa = s4[tid];
    const int4   da = d4[tid];
    const float4 wa = w4[tid];
    const bool hasb = tid < (EPG / 4 - 256);   // 396 quads total
    int4 sb = {0,0,0,0}, db = {0,0,0,0}; float4 wb = {0,0,0,0};
    if (hasb) { sb = s4[tid + 256]; db = d4[tid + 256]; wb = w4[tid + 256]; }

    // --- counts -------------------------------------------------------------
    cnt[tid] = 0u;
    __syncthreads();
    atomicAdd(&cnt[da.x - nbase], 1u); atomicAdd(&cnt[da.y - nbase], 1u);
    atomicAdd(&cnt[da.z - nbase], 1u); atomicAdd(&cnt[da.w - nbase], 1u);
    if (hasb) {
        atomicAdd(&cnt[db.x - nbase], 1u); atomicAdd(&cnt[db.y - nbase], 1u);
        atomicAdd(&cnt[db.z - nbase], 1u); atomicAdd(&cnt[db.w - nbase], 1u);
    }
    __syncthreads();

    // --- exclusive scan: wave shfl scan + cross-wave combine ---------------
    const unsigned v = cnt[tid];
    unsigned inc = v;
#pragma unroll
    for (int s = 1; s < 64; s <<= 1) {
        const unsigned t = (unsigned)__shfl_up((int)inc, s);
        if (lane >= s) inc += t;
    }
    if (lane == 63) wsum[wid] = inc;
    __syncthreads();
    unsigned pre = 0;
    for (int w = 0; w < wid; ++w) pre += wsum[w];
    cursor[tid] = pre + inc - v;   // exclusive prefix
    __syncthreads();

    // --- place edges sorted by dst: pack (f16w<<16)|(dst<<8)|src ------------
    {
        auto place = [&](int s, int d, float w) {
            const int dl = d - nbase;
            const unsigned slot = atomicAdd(&cursor[dl], 1u);
            const __half hw = __float2half_rn(w);
            s_edge[slot] = ((unsigned)__half_as_ushort(hw) << 16)
                         | ((unsigned)dl << 8) | (unsigned)(s - nbase);
        };
        place(sa.x, da.x, wa.x); place(sa.y, da.y, wa.y);
        place(sa.z, da.z, wa.z); place(sa.w, da.w, wa.w);
        if (hasb) {
            place(sb.x, db.x, wb.x); place(sb.y, db.y, wb.y);
            place(sb.z, db.z, wb.z); place(sb.w, db.w, wb.w);
        }
    }
    // pack x (198 x 2 fp32) into half2 rows of bufA (width 1)
    if (tid < NPG) {
        const float2 xv = ((const float2*)x)[nbase + tid];
        bufA[tid] = __builtin_bit_cast(unsigned, __floats2half2_rn(xv.x, xv.y));
    }
    __syncthreads();

    // --- each thread grabs its contiguous run of 6-7 sorted edges -----------
    const int est  = (tid * EPG) >> 8;
    const int een  = ((tid + 1) * EPG) >> 8;
    const int ecnt = een - est;
    unsigned ereg[7];
#pragma unroll
    for (int i = 0; i < 7; ++i) ereg[i] = (i < ecnt) ? s_edge[est + i] : 0u;
    __syncthreads();   // all reads of s_edge done before agg zero clobbers U

    // --- 5 layers: zero agg -> gather -> dense ------------------------------
#define LAYER(CIN, RINW, AGGW, COUT, ROUTW, FIN, FOUT, WR, BR, WQ)            \
    zero_agg<AGGW>(aggF, tid);                                                \
    __syncthreads();                                                          \
    gather<CIN, RINW, AGGW>(FIN, aggF, ereg, ecnt);                           \
    __syncthreads();                                                          \
    dense<CIN, COUT, AGGW, RINW, ROUTW>(aggF, FIN, FOUT, WR, BR, WQ, tid);    \
    __syncthreads();

    LAYER(2,  1,  2,  20, 12, bufA, bufB, wr0, br0, wq0)
    LAYER(20, 12, 20, 15, 8,  bufB, bufA, wr1, br1, wq1)
    LAYER(15, 8,  16, 10, 8,  bufA, bufB, wr2, br2, wq2)
    LAYER(10, 8,  12, 5,  4,  bufB, bufA, wr3, br3, wq3)
    LAYER(5,  4,  8,  2,  1,  bufA, bufB, wr4, br4, wq4)
#undef LAYER

    // --- store tile-transposed fp32: HT[g>>3][node*2+c][g&7] ----------------
    if (tid < NPG) {
        const float2 f = __half22float2(BC2(bufB[tid]));
        float* ht = HT + (size_t)(g >> 3) * (396 * GPB);
        const int jj = g & 7;
        ht[(2 * tid)     * GPB + jj] = f.x;
        ht[(2 * tid + 1) * GPB + jj] = f.y;
    }
}

// ---------------------------------------------------------------------------
// MLP: 8 graphs per block, 512 threads, K-split halves with LDS combine.
// ---------------------------------------------------------------------------
template <int K, int M>
__device__ __forceinline__ void mlp_ks(
    const float* __restrict__ inT,    // [K][8]
    float* __restrict__ outT,         // [M][8]
    float* __restrict__ pbuf,         // [M][8] partial buffer
    const float* __restrict__ wt,     // [K][M]
    const float* __restrict__ bias,
    int o, int h, bool relu)
{
    constexpr int KH = K / 2;
    float acc[GPB];
    if (o < M) {
        const float b0 = h ? 0.f : bias[o];
#pragma unroll
        for (int j = 0; j < GPB; ++j) acc[j] = b0;
        const int k0 = h * KH;
#pragma unroll 4
        for (int k = k0; k < k0 + KH; ++k) {
            const float wv = wt[k * M + o];
            const float4 i0 = *(const float4*)(inT + k * GPB);
            const float4 i1 = *(const float4*)(inT + k * GPB + 4);
            acc[0] = fmaf(wv, i0.x, acc[0]);
            acc[1] = fmaf(wv, i0.y, acc[1]);
            acc[2] = fmaf(wv, i0.z, acc[2]);
            acc[3] = fmaf(wv, i0.w, acc[3]);
            acc[4] = fmaf(wv, i1.x, acc[4]);
            acc[5] = fmaf(wv, i1.y, acc[5]);
            acc[6] = fmaf(wv, i1.z, acc[6]);
            acc[7] = fmaf(wv, i1.w, acc[7]);
        }
        if (h == 1) {
#pragma unroll
            for (int j = 0; j < GPB; ++j) pbuf[o * GPB + j] = acc[j];
        }
    }
    __syncthreads();
    if (h == 0 && o < M) {
#pragma unroll
        for (int j = 0; j < GPB; ++j) {
            const float s = acc[j] + pbuf[o * GPB + j];
            outT[o * GPB + j] = relu ? fmaxf(s, 0.f) : s;
        }
    }
    __syncthreads();
}

__global__ __launch_bounds__(512) void mlp_kernel(
    const float* __restrict__ HT,
    const float* __restrict__ ws,
    const float* __restrict__ lb0, const float* __restrict__ lb1,
    const float* __restrict__ lb2, const float* __restrict__ lb3,
    const float* __restrict__ lb4,
    float* __restrict__ out)
{
    __shared__ __align__(16) float bufA[200 * GPB];
    __shared__ __align__(16) float bufB[100 * GPB];
    __shared__ __align__(16) float pbuf[200 * GPB];

    const int tid = threadIdx.x;
    const int o = tid & 255, h = tid >> 8;
    const float* __restrict__ ht = HT + (size_t)blockIdx.x * (396 * GPB);

    mlp_ks<396, 200>(ht,   bufA, pbuf, ws + WT0_OFF, lb0, o, h, true);
    mlp_ks<200, 100>(bufA, bufB, pbuf, ws + WT1_OFF, lb1, o, h, true);
    mlp_ks<100, 50>(bufB,  bufA, pbuf, ws + WT2_OFF, lb2, o, h, true);
    mlp_ks<50, 10>(bufA,   bufB, pbuf, ws + WT3_OFF, lb3, o, h, true);

    // layer 4 (10 -> 2) + softmax, one thread per graph
    if (tid < GPB) {
        const int j = tid;
        const float* __restrict__ wt4 = ws + WT4_OFF;
        float l0 = lb4[0], l1 = lb4[1];
#pragma unroll
        for (int k = 0; k < 10; ++k) {
            const float vv = bufB[k * GPB + j];
            l0 = fmaf(vv, wt4[k * 2 + 0], l0);
            l1 = fmaf(vv, wt4[k * 2 + 1], l1);
        }
        const float m  = fmaxf(l0, l1);
        const float e0 = __expf(l0 - m), e1 = __expf(l1 - m);
        const float inv = 1.f / (e0 + e1);
        float2 p; p.x = e0 * inv; p.y = e1 * inv;
        ((float2*)out)[blockIdx.x * GPB + j] = p;
    }
}

extern "C" void kernel_launch(void* const* d_in, const int* in_sizes, int n_in,
                              void* d_out, int out_size, void* d_ws, size_t ws_size,
                              hipStream_t stream)
{
    const float* x    = (const float*)d_in[0];
    const int*   eidx = (const int*)  d_in[1];
    const float* ew   = (const float*)d_in[2];

    const float* wr[5]; const float* br[5]; const float* wq[5];
    for (int i = 0; i < 5; ++i) {
        wr[i] = (const float*)d_in[3 + 3 * i];
        br[i] = (const float*)d_in[4 + 3 * i];
        wq[i] = (const float*)d_in[5 + 3 * i];
    }
    const float* lw[5]; const float* lb[5];
    for (int i = 0; i < 5; ++i) {
        lw[i] = (const float*)d_in[18 + 2 * i];
        lb[i] = (const float*)d_in[19 + 2 * i];
    }

    float* ws = (float*)d_ws;

    wtrans_kernel<<<412, 256, 0, stream>>>(lw[0], lw[1], lw[2], lw[3], lw[4], ws);

    conv_kernel<<<NG, 256, 0, stream>>>(
        x, eidx, ew,
        wr[0], br[0], wq[0],
        wr[1], br[1], wq[1],
        wr[2], br[2], wq[2],
        wr[3], br[3], wq[3],
        wr[4], br[4], wq[4],
        ws /* HT at offset 0 */);

    mlp_kernel<<<NG / GPB, 512, 0, stream>>>(
        ws /* HT */, ws /* WT base */,
        lb[0], lb[1], lb[2], lb[3], lb[4],
        (float*)d_out);
}

// Round 5
// 526.256 us; speedup vs baseline: 1.1291x; 1.1291x over previous
//
#include <hip/hip_runtime.h>
#include <hip/hip_fp16.h>

// Problem constants (fixed by the reference)
#define NG    4096        // graphs
#define NPG   198         // nodes per graph
#define EPG   1584        // edges per graph
#define ETOT  (NG * EPG)  // total edges
#define GPB   8           // graphs per MLP block

// Workspace layout (floats):
#define HT_FLOATS (NG / GPB * 396 * GPB)
#define WT0_OFF   (HT_FLOATS)
#define WT1_OFF   (WT0_OFF + 396 * 200)
#define WT2_OFF   (WT1_OFF + 200 * 100)
#define WT3_OFF   (WT2_OFF + 100 * 50)
#define WT4_OFF   (WT3_OFF + 50 * 10)

#define BC2(u) __builtin_bit_cast(__half2, (u))

// ---------------------------------------------------------------------------
// Weight transpose for MLP: WT[k*M+o] = W[o*K+k]
// ---------------------------------------------------------------------------
__global__ __launch_bounds__(256) void wtrans_kernel(
    const float* __restrict__ w0, const float* __restrict__ w1,
    const float* __restrict__ w2, const float* __restrict__ w3,
    const float* __restrict__ w4, float* __restrict__ ws)
{
    const int b = blockIdx.x;
    const float* w; float* t; int K, M, nelem, base;
    if      (b < 310) { w = w0; t = ws + WT0_OFF; K = 396; M = 200; nelem = 79200; base = 0;   }
    else if (b < 389) { w = w1; t = ws + WT1_OFF; K = 200; M = 100; nelem = 20000; base = 310; }
    else if (b < 409) { w = w2; t = ws + WT2_OFF; K = 100; M = 50;  nelem = 5000;  base = 389; }
    else if (b < 411) { w = w3; t = ws + WT3_OFF; K = 50;  M = 10;  nelem = 500;   base = 409; }
    else              { w = w4; t = ws + WT4_OFF; K = 10;  M = 2;   nelem = 20;    base = 411; }
    const int e = (b - base) * 256 + threadIdx.x;
    if (e < nelem) {
        const int o = e / K, k = e - o * K;
        t[k * M + o] = w[e];
    }
}

// ---------------------------------------------------------------------------
// Conv: edge-parallel gather, uniform 8-edge strips (EPG/8 == NPG == 198).
// All LDS buffers are distinct __shared__ objects (no casts/unions) so the
// compiler can pipeline the gather ds_reads past the ds_add_f32 flushes.
// ---------------------------------------------------------------------------

template <int AGGW>
__device__ __forceinline__ void zero_agg(float* __restrict__ agg, int tid)
{
    constexpr int NQ = (NPG * AGGW) / 4;
    const float4 z = make_float4(0.f, 0.f, 0.f, 0.f);
    for (int i = tid; i < NQ; i += 256)
        ((float4*)agg)[i] = z;
}

template <int CIN, int RINW, int AGGW>
__device__ __forceinline__ void gather8(
    const unsigned* __restrict__ fbuf, float* __restrict__ agg,
    const unsigned* __restrict__ er)   // 8 packed edges (registers)
{
    constexpr int MS = (CIN + 1) / 2;
    __half2 ms[MS];
#pragma unroll
    for (int p = 0; p < MS; ++p) ms[p] = __floats2half2_rn(0.f, 0.f);

#pragma unroll
    for (int i = 0; i < 8; ++i) {
        const unsigned e  = er[i];
        const unsigned dl = (e >> 8) & 255u;
        const __half2  w2 = BC2((e >> 16) * 0x10001u);
        const unsigned* row = fbuf + (e & 255u) * RINW;
        if constexpr (RINW == 1) {
            ms[0] = __hfma2(w2, BC2(row[0]), ms[0]);
        } else if constexpr (RINW == 4) {
            const uint4 q = *(const uint4*)row;
            ms[0] = __hfma2(w2, BC2(q.x), ms[0]);
            ms[1] = __hfma2(w2, BC2(q.y), ms[1]);
            ms[2] = __hfma2(w2, BC2(q.z), ms[2]);
        } else if constexpr (RINW == 8) {
            const uint4 q0 = *(const uint4*)row;
            const uint4 q1 = *(const uint4*)(row + 4);
            ms[0] = __hfma2(w2, BC2(q0.x), ms[0]);
            ms[1] = __hfma2(w2, BC2(q0.y), ms[1]);
            ms[2] = __hfma2(w2, BC2(q0.z), ms[2]);
            ms[3] = __hfma2(w2, BC2(q0.w), ms[3]);
            ms[4] = __hfma2(w2, BC2(q1.x), ms[4]);
            if constexpr (MS > 5) {
                ms[5] = __hfma2(w2, BC2(q1.y), ms[5]);
                ms[6] = __hfma2(w2, BC2(q1.z), ms[6]);
                ms[7] = __hfma2(w2, BC2(q1.w), ms[7]);
            }
        } else { // RINW == 12, CIN == 20
            const uint4 q0 = *(const uint4*)row;
            const uint4 q1 = *(const uint4*)(row + 4);
            const uint4 q2 = *(const uint4*)(row + 8);
            ms[0] = __hfma2(w2, BC2(q0.x), ms[0]);
            ms[1] = __hfma2(w2, BC2(q0.y), ms[1]);
            ms[2] = __hfma2(w2, BC2(q0.z), ms[2]);
            ms[3] = __hfma2(w2, BC2(q0.w), ms[3]);
            ms[4] = __hfma2(w2, BC2(q1.x), ms[4]);
            ms[5] = __hfma2(w2, BC2(q1.y), ms[5]);
            ms[6] = __hfma2(w2, BC2(q1.z), ms[6]);
            ms[7] = __hfma2(w2, BC2(q1.w), ms[7]);
            ms[8] = __hfma2(w2, BC2(q2.x), ms[8]);
            ms[9] = __hfma2(w2, BC2(q2.y), ms[9]);
        }
        const bool fl = (i == 7) || (((er[i + 1] >> 8) & 255u) != dl);
        if (fl) {
            float* ar = agg + dl * AGGW;
#pragma unroll
            for (int p = 0; p < MS; ++p) {
                const float2 f = __half22float2(ms[p]);
                atomicAdd(ar + 2 * p, f.x);
                if (2 * p + 1 < CIN) atomicAdd(ar + 2 * p + 1, f.y);
                ms[p] = __floats2half2_rn(0.f, 0.f);
            }
        }
    }
}

template <int CIN, int COUT, int AGGW, int RINW, int ROUTW>
__device__ __forceinline__ void dense(
    const float* __restrict__ agg, const unsigned* __restrict__ fin,
    unsigned* __restrict__ fout,
    const float* __restrict__ wrel, const float* __restrict__ brel,
    const float* __restrict__ wroot, int tid)
{
    if (tid >= NPG) return;

    float av[AGGW];
    if constexpr (AGGW == 2) {
        const float2 v = *(const float2*)(agg + tid * 2);
        av[0] = v.x; av[1] = v.y;
    } else {
#pragma unroll
        for (int qn = 0; qn < AGGW / 4; ++qn) {
            const float4 v = ((const float4*)(agg + tid * AGGW))[qn];
            av[4*qn] = v.x; av[4*qn+1] = v.y; av[4*qn+2] = v.z; av[4*qn+3] = v.w;
        }
    }

    float hv[CIN];
    const unsigned* srow = fin + tid * RINW;
    if constexpr (RINW == 1) {
        const float2 f = __half22float2(BC2(srow[0]));
        hv[0] = f.x; if constexpr (CIN > 1) hv[1] = f.y;
    } else {
#pragma unroll
        for (int qn = 0; qn < RINW / 4; ++qn) {
            const uint4 q = ((const uint4*)srow)[qn];
            const unsigned wd[4] = {q.x, q.y, q.z, q.w};
#pragma unroll
            for (int cc = 0; cc < 4; ++cc) {
                const int w = 4 * qn + cc;
                if (2 * w < CIN) {
                    const float2 f = __half22float2(BC2(wd[cc]));
                    hv[2 * w] = f.x;
                    if (2 * w + 1 < CIN) hv[2 * w + 1] = f.y;
                }
            }
        }
    }

    float outv[COUT];
#pragma unroll
    for (int o = 0; o < COUT; ++o) {
        float acc = brel[o];
#pragma unroll
        for (int c = 0; c < CIN; ++c) {
            acc = fmaf(av[c], wrel[o * CIN + c], acc);
            acc = fmaf(hv[c], wroot[o * CIN + c], acc);
        }
        outv[o] = fmaxf(acc, 0.f);
    }

    unsigned ow[ROUTW];
#pragma unroll
    for (int p = 0; p < ROUTW; ++p) {
        const float lo = (2*p     < COUT) ? outv[2*p]     : 0.f;
        const float hi = (2*p + 1 < COUT) ? outv[2*p + 1] : 0.f;
        ow[p] = __builtin_bit_cast(unsigned, __floats2half2_rn(lo, hi));
    }
    unsigned* orow = fout + tid * ROUTW;
    if constexpr (ROUTW == 1) {
        orow[0] = ow[0];
    } else if constexpr (ROUTW == 4) {
        *(uint4*)orow = make_uint4(ow[0], ow[1], ow[2], ow[3]);
    } else if constexpr (ROUTW == 8) {
        *(uint4*)orow       = make_uint4(ow[0], ow[1], ow[2], ow[3]);
        *(uint4*)(orow + 4) = make_uint4(ow[4], ow[5], ow[6], ow[7]);
    } else { // 12
        *(uint4*)orow       = make_uint4(ow[0], ow[1], ow[2], ow[3]);
        *(uint4*)(orow + 4) = make_uint4(ow[4], ow[5], ow[6], ow[7]);
        *(uint4*)(orow + 8) = make_uint4(ow[8], ow[9], ow[10], ow[11]);
    }
}

__global__ __launch_bounds__(256) void conv_kernel(
    const float* __restrict__ x,
    const int*   __restrict__ eidx,
    const float* __restrict__ ew,
    const float* wr0, const float* br0, const float* wq0,
    const float* wr1, const float* br1, const float* wq1,
    const float* wr2, const float* br2, const float* wq2,
    const float* wr3, const float* br3, const float* wq3,
    const float* wr4, const float* br4, const float* wq4,
    float* __restrict__ HT)
{
    // Distinct __shared__ objects — no unions/casts (alias analysis matters!)
    __shared__ __align__(16) unsigned s_edge[EPG];       // 6336 B
    __shared__ unsigned cnt[256];                        // 1024 B
    __shared__ unsigned cursor[256];                     // 1024 B
    __shared__ unsigned wsum[4];
    __shared__ __align__(16) float    aggF[NPG * 20];    // 15840 B
    __shared__ __align__(16) unsigned bufA[NPG * 8];     // x(1)/A2(8)/A4(4)
    __shared__ __align__(16) unsigned bufB[NPG * 12];    // A1(12)/A3(8)/A5(1)

    const int g = blockIdx.x, tid = threadIdx.x;
    const int ebase = g * EPG, nbase = g * NPG;
    const int lane = tid & 63, wid = tid >> 6;

    // --- load all edges once into registers (396 quads over 256 threads) ----
    const int4*   s4 = (const int4*)(eidx + ebase);
    const int4*   d4 = (const int4*)(eidx + ETOT + ebase);
    const float4* w4 = (const float4*)(ew + ebase);
    const int4   sa = s4[tid];
    const int4   da = d4[tid];
    const float4 wa = w4[tid];
    const bool hasb = tid < (EPG / 4 - 256);   // threads 0..139
    int4 sb = {0,0,0,0}, db = {0,0,0,0}; float4 wb = {0,0,0,0};
    if (hasb) { sb = s4[tid + 256]; db = d4[tid + 256]; wb = w4[tid + 256]; }

    // --- per-destination counts ---------------------------------------------
    cnt[tid] = 0u;
    __syncthreads();
    atomicAdd(&cnt[da.x - nbase], 1u); atomicAdd(&cnt[da.y - nbase], 1u);
    atomicAdd(&cnt[da.z - nbase], 1u); atomicAdd(&cnt[da.w - nbase], 1u);
    if (hasb) {
        atomicAdd(&cnt[db.x - nbase], 1u); atomicAdd(&cnt[db.y - nbase], 1u);
        atomicAdd(&cnt[db.z - nbase], 1u); atomicAdd(&cnt[db.w - nbase], 1u);
    }
    __syncthreads();

    // --- exclusive scan: wave shfl scan + cross-wave combine ----------------
    const unsigned v = cnt[tid];
    unsigned inc = v;
#pragma unroll
    for (int s = 1; s < 64; s <<= 1) {
        const unsigned t = (unsigned)__shfl_up((int)inc, s);
        if (lane >= s) inc += t;
    }
    if (lane == 63) wsum[wid] = inc;
    __syncthreads();
    unsigned pre = 0;
    for (int w = 0; w < wid; ++w) pre += wsum[w];
    cursor[tid] = pre + inc - v;   // exclusive prefix
    __syncthreads();

    // --- place edges sorted by dst: pack (f16w<<16)|(dst<<8)|src ------------
    {
        auto place = [&](int s, int d, float w) {
            const int dl = d - nbase;
            const unsigned slot = atomicAdd(&cursor[dl], 1u);
            const __half hw = __float2half_rn(w);
            s_edge[slot] = ((unsigned)__half_as_ushort(hw) << 16)
                         | ((unsigned)dl << 8) | (unsigned)(s - nbase);
        };
        place(sa.x, da.x, wa.x); place(sa.y, da.y, wa.y);
        place(sa.z, da.z, wa.z); place(sa.w, da.w, wa.w);
        if (hasb) {
            place(sb.x, db.x, wb.x); place(sb.y, db.y, wb.y);
            place(sb.z, db.z, wb.z); place(sb.w, db.w, wb.w);
        }
    }
    // pack x (198 x 2 fp32) into half2 rows of bufA (width 1)
    if (tid < NPG) {
        const float2 xv = ((const float2*)x)[nbase + tid];
        bufA[tid] = __builtin_bit_cast(unsigned, __floats2half2_rn(xv.x, xv.y));
    }
    __syncthreads();

    // --- each thread t<198 owns the uniform 8-edge strip [8t, 8t+8) ---------
    unsigned er[8];
    if (tid < NPG) {
        const uint4 q0 = *(const uint4*)(s_edge + 8 * tid);
        const uint4 q1 = *(const uint4*)(s_edge + 8 * tid + 4);
        er[0] = q0.x; er[1] = q0.y; er[2] = q0.z; er[3] = q0.w;
        er[4] = q1.x; er[5] = q1.y; er[6] = q1.z; er[7] = q1.w;
    }
    __syncthreads();

    // --- 5 layers: zero agg -> gather -> dense ------------------------------
#define LAYER(CIN, RINW, AGGW, COUT, ROUTW, FIN, FOUT, WR, BR, WQ)            \
    zero_agg<AGGW>(aggF, tid);                                                \
    __syncthreads();                                                          \
    if (tid < NPG) gather8<CIN, RINW, AGGW>(FIN, aggF, er);                   \
    __syncthreads();                                                          \
    dense<CIN, COUT, AGGW, RINW, ROUTW>(aggF, FIN, FOUT, WR, BR, WQ, tid);    \
    __syncthreads();

    LAYER(2,  1,  2,  20, 12, bufA, bufB, wr0, br0, wq0)
    LAYER(20, 12, 20, 15, 8,  bufB, bufA, wr1, br1, wq1)
    LAYER(15, 8,  16, 10, 8,  bufA, bufB, wr2, br2, wq2)
    LAYER(10, 8,  12, 5,  4,  bufB, bufA, wr3, br3, wq3)
    LAYER(5,  4,  8,  2,  1,  bufA, bufB, wr4, br4, wq4)
#undef LAYER

    // --- store tile-transposed fp32: HT[g>>3][node*2+c][g&7] ----------------
    if (tid < NPG) {
        const float2 f = __half22float2(BC2(bufB[tid]));
        float* ht = HT + (size_t)(g >> 3) * (396 * GPB);
        const int jj = g & 7;
        ht[(2 * tid)     * GPB + jj] = f.x;
        ht[(2 * tid + 1) * GPB + jj] = f.y;
    }
}

// ---------------------------------------------------------------------------
// MLP kernel (round-3 version): 8 graphs per block, thread = output neuron.
// ---------------------------------------------------------------------------
template <int K, int M>
__device__ __forceinline__ void mlpT(
    const float* __restrict__ inT,    // [K][8], uniform across lanes
    float* __restrict__ outT,         // [M][8]
    const float* __restrict__ wt,     // [K][M] transposed weights
    const float* __restrict__ bias,   // [M]
    int tid, bool relu)
{
    if (tid < M) {
        float acc[GPB];
        const float b = bias[tid];
#pragma unroll
        for (int j = 0; j < GPB; ++j) acc[j] = b;
#pragma unroll 4
        for (int k = 0; k < K; ++k) {
            const float wv = wt[k * M + tid];
            const float4 i0 = *(const float4*)(inT + k * GPB);
            const float4 i1 = *(const float4*)(inT + k * GPB + 4);
            acc[0] = fmaf(wv, i0.x, acc[0]);
            acc[1] = fmaf(wv, i0.y, acc[1]);
            acc[2] = fmaf(wv, i0.z, acc[2]);
            acc[3] = fmaf(wv, i0.w, acc[3]);
            acc[4] = fmaf(wv, i1.x, acc[4]);
            acc[5] = fmaf(wv, i1.y, acc[5]);
            acc[6] = fmaf(wv, i1.z, acc[6]);
            acc[7] = fmaf(wv, i1.w, acc[7]);
        }
#pragma unroll
        for (int j = 0; j < GPB; ++j)
            outT[tid * GPB + j] = relu ? fmaxf(acc[j], 0.f) : acc[j];
    }
}

__global__ __launch_bounds__(256) void mlp_kernel(
    const float* __restrict__ HT,     // [NG/8][396][8]
    const float* __restrict__ ws,     // workspace base (for WT*)
    const float* __restrict__ lb0, const float* __restrict__ lb1,
    const float* __restrict__ lb2, const float* __restrict__ lb3,
    const float* __restrict__ lb4,
    float* __restrict__ out)          // [NG, 2]
{
    __shared__ __align__(16) float bufA[200 * GPB];
    __shared__ __align__(16) float bufB[100 * GPB];

    const int tid = threadIdx.x;
    const float* __restrict__ ht = HT + (size_t)blockIdx.x * (396 * GPB);

    mlpT<396, 200>(ht,   bufA, ws + WT0_OFF, lb0, tid, true);
    __syncthreads();
    mlpT<200, 100>(bufA, bufB, ws + WT1_OFF, lb1, tid, true);
    __syncthreads();
    mlpT<100, 50>(bufB,  bufA, ws + WT2_OFF, lb2, tid, true);
    __syncthreads();
    mlpT<50, 10>(bufA,   bufB, ws + WT3_OFF, lb3, tid, true);
    __syncthreads();

    // layer 4 (10 -> 2) + softmax, one thread per graph
    if (tid < GPB) {
        const int j = tid;
        const float* __restrict__ wt4 = ws + WT4_OFF;
        float l0 = lb4[0], l1 = lb4[1];
#pragma unroll
        for (int k = 0; k < 10; ++k) {
            const float vv = bufB[k * GPB + j];
            l0 = fmaf(vv, wt4[k * 2 + 0], l0);
            l1 = fmaf(vv, wt4[k * 2 + 1], l1);
        }
        const float m  = fmaxf(l0, l1);
        const float e0 = __expf(l0 - m), e1 = __expf(l1 - m);
        const float inv = 1.f / (e0 + e1);
        float2 p; p.x = e0 * inv; p.y = e1 * inv;
        ((float2*)out)[blockIdx.x * GPB + j] = p;
    }
}

extern "C" void kernel_launch(void* const* d_in, const int* in_sizes, int n_in,
                              void* d_out, int out_size, void* d_ws, size_t ws_size,
                              hipStream_t stream)
{
    const float* x    = (const float*)d_in[0];
    const int*   eidx = (const int*)  d_in[1];
    const float* ew   = (const float*)d_in[2];

    const float* wr[5]; const float* br[5]; const float* wq[5];
    for (int i = 0; i < 5; ++i) {
        wr[i] = (const float*)d_in[3 + 3 * i];
        br[i] = (const float*)d_in[4 + 3 * i];
        wq[i] = (const float*)d_in[5 + 3 * i];
    }
    const float* lw[5]; const float* lb[5];
    for (int i = 0; i < 5; ++i) {
        lw[i] = (const float*)d_in[18 + 2 * i];
        lb[i] = (const float*)d_in[19 + 2 * i];
    }

    float* ws = (float*)d_ws;

    wtrans_kernel<<<412, 256, 0, stream>>>(lw[0], lw[1], lw[2], lw[3], lw[4], ws);

    conv_kernel<<<NG, 256, 0, stream>>>(
        x, eidx, ew,
        wr[0], br[0], wq[0],
        wr[1], br[1], wq[1],
        wr[2], br[2], wq[2],
        wr[3], br[3], wq[3],
        wr[4], br[4], wq[4],
        ws /* HT at offset 0 */);

    mlp_kernel<<<NG / GPB, 256, 0, stream>>>(
        ws /* HT */, ws /* WT base */,
        lb[0], lb[1], lb[2], lb[3], lb[4],
        (float*)d_out);
}

// Round 6
// 146.611 us; speedup vs baseline: 4.0527x; 3.5895x over previous
//
#include <hip/hip_runtime.h>
#include <hip/hip_fp16.h>

// Problem constants (fixed by the reference)
#define NG    4096        // graphs
#define NPG   198         // nodes per graph
#define EPG   1584        // edges per graph
#define ETOT  (NG * EPG)  // total edges
#define GPB   4           // graphs per MLP block

// Workspace layout (floats):
#define HT_FLOATS (NG * 396)
#define WT0_OFF   (HT_FLOATS)
#define WT1_OFF   (WT0_OFF + 396 * 200)
#define WT2_OFF   (WT1_OFF + 200 * 100)
#define WT3_OFF   (WT2_OFF + 100 * 50)
#define WT4_OFF   (WT3_OFF + 50 * 10)

#define BC2(u) __builtin_bit_cast(__half2, (u))

// ---------------------------------------------------------------------------
// Weight transpose for MLP: WT[k*M+o] = W[o*K+k]
// ---------------------------------------------------------------------------
__global__ __launch_bounds__(256) void wtrans_kernel(
    const float* __restrict__ w0, const float* __restrict__ w1,
    const float* __restrict__ w2, const float* __restrict__ w3,
    const float* __restrict__ w4, float* __restrict__ ws)
{
    const int b = blockIdx.x;
    const float* w; float* t; int K, M, nelem, base;
    if      (b < 310) { w = w0; t = ws + WT0_OFF; K = 396; M = 200; nelem = 79200; base = 0;   }
    else if (b < 389) { w = w1; t = ws + WT1_OFF; K = 200; M = 100; nelem = 20000; base = 310; }
    else if (b < 409) { w = w2; t = ws + WT2_OFF; K = 100; M = 50;  nelem = 5000;  base = 389; }
    else if (b < 411) { w = w3; t = ws + WT3_OFF; K = 50;  M = 10;  nelem = 500;   base = 409; }
    else              { w = w4; t = ws + WT4_OFF; K = 10;  M = 2;   nelem = 20;    base = 411; }
    const int e = (b - base) * 256 + threadIdx.x;
    if (e < nelem) {
        const int o = e / K, k = e - o * K;
        t[k * M + o] = w[e];
    }
}

// ---------------------------------------------------------------------------
// Conv: node-per-thread gather (round-3 structure — no LDS writes in the hot
// loop), plus (a) degree-sorted node->thread mapping to kill trip-count
// divergence, (b) 12-word (48 B) row stride so b128 row reads start in all 8
// 16B-aligned bank classes (stride 8 words only hits 4).
// ---------------------------------------------------------------------------

template <int CIN, int COUT, int SIN, int SOUT>
__device__ __forceinline__ void conv_layer_h(
    const unsigned* __restrict__ h_in,   // rows stride SIN (half2 words)
    unsigned* __restrict__ h_out,        // rows stride SOUT
    const unsigned* __restrict__ s_edge, // (f16w<<16)|src, sorted by dst
    const unsigned* __restrict__ row_start,
    const unsigned* __restrict__ perm,   // degree-sorted node order
    const float* __restrict__ wrel, const float* __restrict__ brel,
    const float* __restrict__ wroot, int tid)
{
    if (tid >= NPG) return;
    const int node = (int)perm[tid];
    constexpr int MS = (CIN + 1) / 2;

    __half2 ms[MS];
#pragma unroll
    for (int p = 0; p < MS; ++p) ms[p] = __floats2half2_rn(0.f, 0.f);

    const unsigned jb = row_start[node], je = row_start[node + 1];
    for (unsigned j = jb; j < je; ++j) {
        const unsigned e  = s_edge[j];
        const __half2  w2 = BC2((e >> 16) * 0x10001u);
        const unsigned* row = h_in + (e & 0xFFFFu) * SIN;
        if constexpr (SIN == 1) {
            ms[0] = __hfma2(w2, BC2(row[0]), ms[0]);
        } else {
            const uint4 q0 = *(const uint4*)row;
            ms[0] = __hfma2(w2, BC2(q0.x), ms[0]);
            if constexpr (MS > 1) ms[1] = __hfma2(w2, BC2(q0.y), ms[1]);
            if constexpr (MS > 2) ms[2] = __hfma2(w2, BC2(q0.z), ms[2]);
            if constexpr (MS > 3) ms[3] = __hfma2(w2, BC2(q0.w), ms[3]);
            if constexpr (MS > 4) {
                const uint4 q1 = *(const uint4*)(row + 4);
                ms[4] = __hfma2(w2, BC2(q1.x), ms[4]);
                if constexpr (MS > 5) ms[5] = __hfma2(w2, BC2(q1.y), ms[5]);
                if constexpr (MS > 6) ms[6] = __hfma2(w2, BC2(q1.z), ms[6]);
                if constexpr (MS > 7) ms[7] = __hfma2(w2, BC2(q1.w), ms[7]);
            }
            if constexpr (MS > 8) {
                const uint4 q2 = *(const uint4*)(row + 8);
                ms[8] = __hfma2(w2, BC2(q2.x), ms[8]);
                if constexpr (MS > 9) ms[9] = __hfma2(w2, BC2(q2.y), ms[9]);
            }
        }
    }

    // unpack aggregate to f32
    float aggf[CIN];
#pragma unroll
    for (int p = 0; p < MS; ++p) {
        const float2 fa = __half22float2(ms[p]);
        aggf[2 * p] = fa.x;
        if (2 * p + 1 < CIN) aggf[2 * p + 1] = fa.y;
    }

    // own row to f32
    float hv[CIN];
    {
        const unsigned* me = h_in + node * SIN;
        unsigned mw[MS];
        if constexpr (SIN == 1) {
            mw[0] = me[0];
        } else {
            const uint4 q0 = *(const uint4*)me;
            mw[0] = q0.x;
            if constexpr (MS > 1) mw[1] = q0.y;
            if constexpr (MS > 2) mw[2] = q0.z;
            if constexpr (MS > 3) mw[3] = q0.w;
            if constexpr (MS > 4) {
                const uint4 q1 = *(const uint4*)(me + 4);
                mw[4] = q1.x;
                if constexpr (MS > 5) mw[5] = q1.y;
                if constexpr (MS > 6) mw[6] = q1.z;
                if constexpr (MS > 7) mw[7] = q1.w;
            }
            if constexpr (MS > 8) {
                const uint4 q2 = *(const uint4*)(me + 8);
                mw[8] = q2.x;
                if constexpr (MS > 9) mw[9] = q2.y;
            }
        }
#pragma unroll
        for (int p = 0; p < MS; ++p) {
            const float2 f = __half22float2(BC2(mw[p]));
            hv[2 * p] = f.x;
            if (2 * p + 1 < CIN) hv[2 * p + 1] = f.y;
        }
    }

    float outv[COUT];
#pragma unroll
    for (int o = 0; o < COUT; ++o) {
        float acc = brel[o];
#pragma unroll
        for (int c = 0; c < CIN; ++c) {
            acc = fmaf(aggf[c], wrel[o * CIN + c], acc);
            acc = fmaf(hv[c],   wroot[o * CIN + c], acc);
        }
        outv[o] = fmaxf(acc, 0.f);
    }

    if constexpr (SOUT == 1) {
        h_out[node] = __builtin_bit_cast(unsigned,
            __floats2half2_rn(outv[0], COUT > 1 ? outv[1] : 0.f));
    } else {
        constexpr int W  = (COUT + 1) / 2;
        constexpr int WQ = (W + 3) / 4;
        unsigned ow[WQ * 4];
#pragma unroll
        for (int p = 0; p < WQ * 4; ++p) {
            const float lo = (2 * p     < COUT) ? outv[2 * p]     : 0.f;
            const float hi = (2 * p + 1 < COUT) ? outv[2 * p + 1] : 0.f;
            ow[p] = __builtin_bit_cast(unsigned, __floats2half2_rn(lo, hi));
        }
        unsigned* orow = h_out + node * SOUT;
#pragma unroll
        for (int q = 0; q < WQ; ++q)
            *(uint4*)(orow + 4 * q) =
                make_uint4(ow[4*q], ow[4*q+1], ow[4*q+2], ow[4*q+3]);
    }
}

__global__ __launch_bounds__(256) void conv_kernel(
    const float* __restrict__ x,
    const int*   __restrict__ eidx,
    const float* __restrict__ ew,
    const float* wr0, const float* br0, const float* wq0,
    const float* wr1, const float* br1, const float* wq1,
    const float* wr2, const float* br2, const float* wq2,
    const float* wr3, const float* br3, const float* wq3,
    const float* wr4, const float* br4, const float* wq4,
    float* __restrict__ HT)              // [NG/4][396][4]
{
    __shared__ __align__(16) unsigned s_edge[EPG];       // 6336 B
    __shared__ unsigned cnt[256];
    __shared__ unsigned cursor[256];
    __shared__ unsigned row_start[NPG + 1];
    __shared__ unsigned wsum[4];
    __shared__ unsigned dhist[64];
    __shared__ unsigned dcur[64];
    __shared__ unsigned perm[NPG];
    __shared__ __align__(16) unsigned bufA[NPG * 12];    // 9504 B
    __shared__ __align__(16) unsigned bufB[NPG * 12];    // 9504 B

    const int g = blockIdx.x, tid = threadIdx.x;
    const int ebase = g * EPG, nbase = g * NPG;
    const int lane = tid & 63, wid = tid >> 6;

    // --- load all edges once into registers (396 quads over 256 threads) ----
    const int4*   s4 = (const int4*)(eidx + ebase);
    const int4*   d4 = (const int4*)(eidx + ETOT + ebase);
    const float4* w4 = (const float4*)(ew + ebase);
    const int4   sa = s4[tid];
    const int4   da = d4[tid];
    const float4 wa = w4[tid];
    const bool hasb = tid < (EPG / 4 - 256);   // threads 0..139
    int4 sb = {0,0,0,0}, db = {0,0,0,0}; float4 wb = {0,0,0,0};
    if (hasb) { sb = s4[tid + 256]; db = d4[tid + 256]; wb = w4[tid + 256]; }

    // --- per-destination counts ---------------------------------------------
    cnt[tid] = 0u;
    __syncthreads();
    atomicAdd(&cnt[da.x - nbase], 1u); atomicAdd(&cnt[da.y - nbase], 1u);
    atomicAdd(&cnt[da.z - nbase], 1u); atomicAdd(&cnt[da.w - nbase], 1u);
    if (hasb) {
        atomicAdd(&cnt[db.x - nbase], 1u); atomicAdd(&cnt[db.y - nbase], 1u);
        atomicAdd(&cnt[db.z - nbase], 1u); atomicAdd(&cnt[db.w - nbase], 1u);
    }
    __syncthreads();

    // --- exclusive scan (wave shfl + cross-wave combine) --------------------
    const unsigned v = cnt[tid];
    unsigned inc = v;
#pragma unroll
    for (int s = 1; s < 64; s <<= 1) {
        const unsigned t = (unsigned)__shfl_up((int)inc, s);
        if (lane >= s) inc += t;
    }
    if (lane == 63) wsum[wid] = inc;
    __syncthreads();
    unsigned pre = 0;
    for (int w = 0; w < wid; ++w) pre += wsum[w];
    const unsigned excl = pre + inc - v;
    if (tid <= NPG) row_start[tid] = excl;   // row_start[198] == EPG
    if (tid < NPG)  cursor[tid]    = excl;
    __syncthreads();

    // --- place edges sorted by dst: pack (f16w<<16)|src ---------------------
    {
        auto place = [&](int s, int d, float w) {
            const int dl = d - nbase;
            const unsigned slot = atomicAdd(&cursor[dl], 1u);
            const __half hw = __float2half_rn(w);
            s_edge[slot] = ((unsigned)__half_as_ushort(hw) << 16)
                         | (unsigned)(s - nbase);
        };
        place(sa.x, da.x, wa.x); place(sa.y, da.y, wa.y);
        place(sa.z, da.z, wa.z); place(sa.w, da.w, wa.w);
        if (hasb) {
            place(sb.x, db.x, wb.x); place(sb.y, db.y, wb.y);
            place(sb.z, db.z, wb.z); place(sb.w, db.w, wb.w);
        }
    }

    // pack x (198 x 2 fp32) into half2 words of bufA (stride 1)
    if (tid < NPG) {
        const float2 xv = ((const float2*)x)[nbase + tid];
        bufA[tid] = __builtin_bit_cast(unsigned, __floats2half2_rn(xv.x, xv.y));
    }

    // --- degree-sorted permutation (counting sort over 64 degree bins) ------
    if (tid < 64) dhist[tid] = 0u;
    __syncthreads();
    unsigned mydeg = 0u;
    if (tid < NPG) {
        mydeg = cnt[tid]; if (mydeg > 63u) mydeg = 63u;
        atomicAdd(&dhist[mydeg], 1u);
    }
    __syncthreads();
    if (tid < 64) {
        const unsigned dv = dhist[tid];
        unsigned sc = dv;
#pragma unroll
        for (int s = 1; s < 64; s <<= 1) {
            const unsigned t = (unsigned)__shfl_up((int)sc, s);
            if (lane >= s) sc += t;
        }
        dcur[tid] = sc - dv;   // exclusive
    }
    __syncthreads();
    if (tid < NPG) {
        const unsigned pos = atomicAdd(&dcur[mydeg], 1u);
        perm[pos] = (unsigned)tid;
    }
    __syncthreads();

    // --- 5 layers ------------------------------------------------------------
    conv_layer_h<2,  20, 1,  12>(bufA, bufB, s_edge, row_start, perm, wr0, br0, wq0, tid);
    __syncthreads();
    conv_layer_h<20, 15, 12, 12>(bufB, bufA, s_edge, row_start, perm, wr1, br1, wq1, tid);
    __syncthreads();
    conv_layer_h<15, 10, 12, 12>(bufA, bufB, s_edge, row_start, perm, wr2, br2, wq2, tid);
    __syncthreads();
    conv_layer_h<10, 5,  12, 12>(bufB, bufA, s_edge, row_start, perm, wr3, br3, wq3, tid);
    __syncthreads();
    conv_layer_h<5,  2,  12, 1 >(bufA, bufB, s_edge, row_start, perm, wr4, br4, wq4, tid);
    __syncthreads();

    // --- store tile-transposed fp32: HT[g>>2][node*2+c][g&3] ----------------
    if (tid < NPG) {
        const float2 f = __half22float2(BC2(bufB[tid]));
        float* ht = HT + (size_t)(g >> 2) * (396 * GPB);
        const int jj = g & 3;
        ht[(2 * tid)     * GPB + jj] = f.x;
        ht[(2 * tid + 1) * GPB + jj] = f.y;
    }
}

// ---------------------------------------------------------------------------
// MLP: 4 graphs per block (1024 blocks -> 4 blocks/CU, 16 waves/CU).
// Thread = output neuron, 4 accumulators; input staged in LDS (broadcast).
// ---------------------------------------------------------------------------
template <int K, int M>
__device__ __forceinline__ void mlpT(
    const float* __restrict__ inT,    // [K][4] in LDS, uniform across lanes
    float* __restrict__ outT,         // [M][4]
    const float* __restrict__ wt,     // [K][M] transposed weights
    const float* __restrict__ bias,
    int tid, bool relu)
{
    if (tid < M) {
        const float b = bias[tid];
        float a0 = b, a1 = b, a2 = b, a3 = b;
#pragma unroll 4
        for (int k = 0; k < K; ++k) {
            const float wv = wt[k * M + tid];
            const float4 iv = *(const float4*)(inT + k * 4);
            a0 = fmaf(wv, iv.x, a0);
            a1 = fmaf(wv, iv.y, a1);
            a2 = fmaf(wv, iv.z, a2);
            a3 = fmaf(wv, iv.w, a3);
        }
        float4 r;
        r.x = relu ? fmaxf(a0, 0.f) : a0;
        r.y = relu ? fmaxf(a1, 0.f) : a1;
        r.z = relu ? fmaxf(a2, 0.f) : a2;
        r.w = relu ? fmaxf(a3, 0.f) : a3;
        *(float4*)(outT + tid * 4) = r;
    }
}

__global__ __launch_bounds__(256) void mlp_kernel(
    const float* __restrict__ HT,     // [NG/4][396][4]
    const float* __restrict__ ws,     // workspace base (for WT*)
    const float* __restrict__ lb0, const float* __restrict__ lb1,
    const float* __restrict__ lb2, const float* __restrict__ lb3,
    const float* __restrict__ lb4,
    float* __restrict__ out)          // [NG, 2]
{
    __shared__ __align__(16) float bufI[396 * 4];
    __shared__ __align__(16) float bufA[200 * 4];
    __shared__ __align__(16) float bufB[100 * 4];

    const int tid = threadIdx.x;
    const float* __restrict__ ht = HT + (size_t)blockIdx.x * (396 * 4);

    for (int t = tid; t < 396; t += 256)
        ((float4*)bufI)[t] = ((const float4*)ht)[t];
    __syncthreads();

    mlpT<396, 200>(bufI, bufA, ws + WT0_OFF, lb0, tid, true);
    __syncthreads();
    mlpT<200, 100>(bufA, bufB, ws + WT1_OFF, lb1, tid, true);
    __syncthreads();
    mlpT<100, 50>(bufB,  bufA, ws + WT2_OFF, lb2, tid, true);
    __syncthreads();
    mlpT<50, 10>(bufA,   bufB, ws + WT3_OFF, lb3, tid, true);
    __syncthreads();

    // layer 4 (10 -> 2) + softmax, one thread per graph
    if (tid < GPB) {
        const int j = tid;
        const float* __restrict__ wt4 = ws + WT4_OFF;
        float l0 = lb4[0], l1 = lb4[1];
#pragma unroll
        for (int k = 0; k < 10; ++k) {
            const float vv = bufB[k * GPB + j];
            l0 = fmaf(vv, wt4[k * 2 + 0], l0);
            l1 = fmaf(vv, wt4[k * 2 + 1], l1);
        }
        const float m  = fmaxf(l0, l1);
        const float e0 = __expf(l0 - m), e1 = __expf(l1 - m);
        const float inv = 1.f / (e0 + e1);
        float2 p; p.x = e0 * inv; p.y = e1 * inv;
        ((float2*)out)[blockIdx.x * GPB + j] = p;
    }
}

extern "C" void kernel_launch(void* const* d_in, const int* in_sizes, int n_in,
                              void* d_out, int out_size, void* d_ws, size_t ws_size,
                              hipStream_t stream)
{
    const float* x    = (const float*)d_in[0];
    const int*   eidx = (const int*)  d_in[1];
    const float* ew   = (const float*)d_in[2];

    const float* wr[5]; const float* br[5]; const float* wq[5];
    for (int i = 0; i < 5; ++i) {
        wr[i] = (const float*)d_in[3 + 3 * i];
        br[i] = (const float*)d_in[4 + 3 * i];
        wq[i] = (const float*)d_in[5 + 3 * i];
    }
    const float* lw[5]; const float* lb[5];
    for (int i = 0; i < 5; ++i) {
        lw[i] = (const float*)d_in[18 + 2 * i];
        lb[i] = (const float*)d_in[19 + 2 * i];
    }

    float* ws = (float*)d_ws;

    wtrans_kernel<<<412, 256, 0, stream>>>(lw[0], lw[1], lw[2], lw[3], lw[4], ws);

    conv_kernel<<<NG, 256, 0, stream>>>(
        x, eidx, ew,
        wr[0], br[0], wq[0],
        wr[1], br[1], wq[1],
        wr[2], br[2], wq[2],
        wr[3], br[3], wq[3],
        wr[4], br[4], wq[4],
        ws /* HT at offset 0 */);

    mlp_kernel<<<NG / GPB, 256, 0, stream>>>(
        ws /* HT */, ws /* WT base */,
        lb[0], lb[1], lb[2], lb[3], lb[4],
        (float*)d_out);
}

// Round 7
// 129.564 us; speedup vs baseline: 4.5859x; 1.1316x over previous
//
#include <hip/hip_runtime.h>
#include <hip/hip_fp16.h>

// Problem constants (fixed by the reference)
#define NG    4096        // graphs
#define NPG   198         // nodes per graph
#define EPG   1584        // edges per graph
#define ETOT  (NG * EPG)  // total edges

#define BC2(u) __builtin_bit_cast(__half2, (u))

typedef _Float16 f16x4 __attribute__((ext_vector_type(4)));
typedef float    f32x4 __attribute__((ext_vector_type(4)));

// Workspace layout (f16 units):
//   H    [NG][396] f16                      = 1,622,016 f16
//   WTB0 [25][208][16] f16  (83200)  @ +0
//   WTB1 [13][112][16] f16  (23296)  @ +83200
//   WTB2 [ 7][ 64][16] f16  ( 7168)  @ +106496
//   WTB3 [ 4][ 16][16] f16  ( 1024)  @ +113664
#define H_F16S    (NG * 396)
#define WTB1_OFF  83200
#define WTB2_OFF  106496
#define WTB3_OFF  113664
#define WTB_TOTAL 114688

// ---------------------------------------------------------------------------
// Weight pack: WTB[kc][n][ki] = (f16)W[n][kc*16+ki], zero-padded in K and N.
// ---------------------------------------------------------------------------
__global__ __launch_bounds__(256) void wtrans16_kernel(
    const float* __restrict__ w0, const float* __restrict__ w1,
    const float* __restrict__ w2, const float* __restrict__ w3,
    _Float16* __restrict__ wtb)
{
    const int idx = blockIdx.x * 256 + threadIdx.x;
    const float* w; int K, N, NPAD, rel;
    if (idx < 83200)       { w = w0; K = 396; N = 200; NPAD = 208; rel = idx; }
    else if (idx < 106496) { w = w1; K = 200; N = 100; NPAD = 112; rel = idx - 83200; }
    else if (idx < 113664) { w = w2; K = 100; N = 50;  NPAD = 64;  rel = idx - 106496; }
    else                   { w = w3; K = 50;  N = 10;  NPAD = 16;  rel = idx - 113664; }
    const int span = NPAD * 16;
    const int kc = rel / span;
    const int r  = rel - kc * span;
    const int n  = r >> 4, ki = r & 15;
    const int k  = kc * 16 + ki;
    const float v = (n < N && k < K) ? w[n * K + k] : 0.f;
    wtb[idx] = (_Float16)v;
}

// ---------------------------------------------------------------------------
// Conv: node-per-thread gather (round-6 structure, unchanged except the final
// store is now row-major f16 H[g][396]).
// ---------------------------------------------------------------------------

template <int CIN, int COUT, int SIN, int SOUT>
__device__ __forceinline__ void conv_layer_h(
    const unsigned* __restrict__ h_in,   // rows stride SIN (half2 words)
    unsigned* __restrict__ h_out,        // rows stride SOUT
    const unsigned* __restrict__ s_edge, // (f16w<<16)|src, sorted by dst
    const unsigned* __restrict__ row_start,
    const unsigned* __restrict__ perm,   // degree-sorted node order
    const float* __restrict__ wrel, const float* __restrict__ brel,
    const float* __restrict__ wroot, int tid)
{
    if (tid >= NPG) return;
    const int node = (int)perm[tid];
    constexpr int MS = (CIN + 1) / 2;

    __half2 ms[MS];
#pragma unroll
    for (int p = 0; p < MS; ++p) ms[p] = __floats2half2_rn(0.f, 0.f);

    const unsigned jb = row_start[node], je = row_start[node + 1];
    for (unsigned j = jb; j < je; ++j) {
        const unsigned e  = s_edge[j];
        const __half2  w2 = BC2((e >> 16) * 0x10001u);
        const unsigned* row = h_in + (e & 0xFFFFu) * SIN;
        if constexpr (SIN == 1) {
            ms[0] = __hfma2(w2, BC2(row[0]), ms[0]);
        } else {
            const uint4 q0 = *(const uint4*)row;
            ms[0] = __hfma2(w2, BC2(q0.x), ms[0]);
            if constexpr (MS > 1) ms[1] = __hfma2(w2, BC2(q0.y), ms[1]);
            if constexpr (MS > 2) ms[2] = __hfma2(w2, BC2(q0.z), ms[2]);
            if constexpr (MS > 3) ms[3] = __hfma2(w2, BC2(q0.w), ms[3]);
            if constexpr (MS > 4) {
                const uint4 q1 = *(const uint4*)(row + 4);
                ms[4] = __hfma2(w2, BC2(q1.x), ms[4]);
                if constexpr (MS > 5) ms[5] = __hfma2(w2, BC2(q1.y), ms[5]);
                if constexpr (MS > 6) ms[6] = __hfma2(w2, BC2(q1.z), ms[6]);
                if constexpr (MS > 7) ms[7] = __hfma2(w2, BC2(q1.w), ms[7]);
            }
            if constexpr (MS > 8) {
                const uint4 q2 = *(const uint4*)(row + 8);
                ms[8] = __hfma2(w2, BC2(q2.x), ms[8]);
                if constexpr (MS > 9) ms[9] = __hfma2(w2, BC2(q2.y), ms[9]);
            }
        }
    }

    float aggf[CIN];
#pragma unroll
    for (int p = 0; p < MS; ++p) {
        const float2 fa = __half22float2(ms[p]);
        aggf[2 * p] = fa.x;
        if (2 * p + 1 < CIN) aggf[2 * p + 1] = fa.y;
    }

    float hv[CIN];
    {
        const unsigned* me = h_in + node * SIN;
        unsigned mw[MS];
        if constexpr (SIN == 1) {
            mw[0] = me[0];
        } else {
            const uint4 q0 = *(const uint4*)me;
            mw[0] = q0.x;
            if constexpr (MS > 1) mw[1] = q0.y;
            if constexpr (MS > 2) mw[2] = q0.z;
            if constexpr (MS > 3) mw[3] = q0.w;
            if constexpr (MS > 4) {
                const uint4 q1 = *(const uint4*)(me + 4);
                mw[4] = q1.x;
                if constexpr (MS > 5) mw[5] = q1.y;
                if constexpr (MS > 6) mw[6] = q1.z;
                if constexpr (MS > 7) mw[7] = q1.w;
            }
            if constexpr (MS > 8) {
                const uint4 q2 = *(const uint4*)(me + 8);
                mw[8] = q2.x;
                if constexpr (MS > 9) mw[9] = q2.y;
            }
        }
#pragma unroll
        for (int p = 0; p < MS; ++p) {
            const float2 f = __half22float2(BC2(mw[p]));
            hv[2 * p] = f.x;
            if (2 * p + 1 < CIN) hv[2 * p + 1] = f.y;
        }
    }

    float outv[COUT];
#pragma unroll
    for (int o = 0; o < COUT; ++o) {
        float acc = brel[o];
#pragma unroll
        for (int c = 0; c < CIN; ++c) {
            acc = fmaf(aggf[c], wrel[o * CIN + c], acc);
            acc = fmaf(hv[c],   wroot[o * CIN + c], acc);
        }
        outv[o] = fmaxf(acc, 0.f);
    }

    if constexpr (SOUT == 1) {
        h_out[node] = __builtin_bit_cast(unsigned,
            __floats2half2_rn(outv[0], COUT > 1 ? outv[1] : 0.f));
    } else {
        constexpr int W  = (COUT + 1) / 2;
        constexpr int WQ = (W + 3) / 4;
        unsigned ow[WQ * 4];
#pragma unroll
        for (int p = 0; p < WQ * 4; ++p) {
            const float lo = (2 * p     < COUT) ? outv[2 * p]     : 0.f;
            const float hi = (2 * p + 1 < COUT) ? outv[2 * p + 1] : 0.f;
            ow[p] = __builtin_bit_cast(unsigned, __floats2half2_rn(lo, hi));
        }
        unsigned* orow = h_out + node * SOUT;
#pragma unroll
        for (int q = 0; q < WQ; ++q)
            *(uint4*)(orow + 4 * q) =
                make_uint4(ow[4*q], ow[4*q+1], ow[4*q+2], ow[4*q+3]);
    }
}

__global__ __launch_bounds__(256) void conv_kernel(
    const float* __restrict__ x,
    const int*   __restrict__ eidx,
    const float* __restrict__ ew,
    const float* wr0, const float* br0, const float* wq0,
    const float* wr1, const float* br1, const float* wq1,
    const float* wr2, const float* br2, const float* wq2,
    const float* wr3, const float* br3, const float* wq3,
    const float* wr4, const float* br4, const float* wq4,
    _Float16* __restrict__ H)            // row-major [NG][396] f16
{
    __shared__ __align__(16) unsigned s_edge[EPG];
    __shared__ unsigned cnt[256];
    __shared__ unsigned cursor[256];
    __shared__ unsigned row_start[NPG + 1];
    __shared__ unsigned wsum[4];
    __shared__ unsigned dhist[64];
    __shared__ unsigned dcur[64];
    __shared__ unsigned perm[NPG];
    __shared__ __align__(16) unsigned bufA[NPG * 12];
    __shared__ __align__(16) unsigned bufB[NPG * 12];

    const int g = blockIdx.x, tid = threadIdx.x;
    const int ebase = g * EPG, nbase = g * NPG;
    const int lane = tid & 63, wid = tid >> 6;

    const int4*   s4 = (const int4*)(eidx + ebase);
    const int4*   d4 = (const int4*)(eidx + ETOT + ebase);
    const float4* w4 = (const float4*)(ew + ebase);
    const int4   sa = s4[tid];
    const int4   da = d4[tid];
    const float4 wa = w4[tid];
    const bool hasb = tid < (EPG / 4 - 256);
    int4 sb = {0,0,0,0}, db = {0,0,0,0}; float4 wb = {0,0,0,0};
    if (hasb) { sb = s4[tid + 256]; db = d4[tid + 256]; wb = w4[tid + 256]; }

    cnt[tid] = 0u;
    __syncthreads();
    atomicAdd(&cnt[da.x - nbase], 1u); atomicAdd(&cnt[da.y - nbase], 1u);
    atomicAdd(&cnt[da.z - nbase], 1u); atomicAdd(&cnt[da.w - nbase], 1u);
    if (hasb) {
        atomicAdd(&cnt[db.x - nbase], 1u); atomicAdd(&cnt[db.y - nbase], 1u);
        atomicAdd(&cnt[db.z - nbase], 1u); atomicAdd(&cnt[db.w - nbase], 1u);
    }
    __syncthreads();

    const unsigned v = cnt[tid];
    unsigned inc = v;
#pragma unroll
    for (int s = 1; s < 64; s <<= 1) {
        const unsigned t = (unsigned)__shfl_up((int)inc, s);
        if (lane >= s) inc += t;
    }
    if (lane == 63) wsum[wid] = inc;
    __syncthreads();
    unsigned pre = 0;
    for (int w = 0; w < wid; ++w) pre += wsum[w];
    const unsigned excl = pre + inc - v;
    if (tid <= NPG) row_start[tid] = excl;
    if (tid < NPG)  cursor[tid]    = excl;
    __syncthreads();

    {
        auto place = [&](int s, int d, float w) {
            const int dl = d - nbase;
            const unsigned slot = atomicAdd(&cursor[dl], 1u);
            const __half hw = __float2half_rn(w);
            s_edge[slot] = ((unsigned)__half_as_ushort(hw) << 16)
                         | (unsigned)(s - nbase);
        };
        place(sa.x, da.x, wa.x); place(sa.y, da.y, wa.y);
        place(sa.z, da.z, wa.z); place(sa.w, da.w, wa.w);
        if (hasb) {
            place(sb.x, db.x, wb.x); place(sb.y, db.y, wb.y);
            place(sb.z, db.z, wb.z); place(sb.w, db.w, wb.w);
        }
    }

    if (tid < NPG) {
        const float2 xv = ((const float2*)x)[nbase + tid];
        bufA[tid] = __builtin_bit_cast(unsigned, __floats2half2_rn(xv.x, xv.y));
    }

    if (tid < 64) dhist[tid] = 0u;
    __syncthreads();
    unsigned mydeg = 0u;
    if (tid < NPG) {
        mydeg = cnt[tid]; if (mydeg > 63u) mydeg = 63u;
        atomicAdd(&dhist[mydeg], 1u);
    }
    __syncthreads();
    if (tid < 64) {
        const unsigned dv = dhist[tid];
        unsigned sc = dv;
#pragma unroll
        for (int s = 1; s < 64; s <<= 1) {
            const unsigned t = (unsigned)__shfl_up((int)sc, s);
            if (lane >= s) sc += t;
        }
        dcur[tid] = sc - dv;
    }
    __syncthreads();
    if (tid < NPG) {
        const unsigned pos = atomicAdd(&dcur[mydeg], 1u);
        perm[pos] = (unsigned)tid;
    }
    __syncthreads();

    conv_layer_h<2,  20, 1,  12>(bufA, bufB, s_edge, row_start, perm, wr0, br0, wq0, tid);
    __syncthreads();
    conv_layer_h<20, 15, 12, 12>(bufB, bufA, s_edge, row_start, perm, wr1, br1, wq1, tid);
    __syncthreads();
    conv_layer_h<15, 10, 12, 12>(bufA, bufB, s_edge, row_start, perm, wr2, br2, wq2, tid);
    __syncthreads();
    conv_layer_h<10, 5,  12, 12>(bufB, bufA, s_edge, row_start, perm, wr3, br3, wq3, tid);
    __syncthreads();
    conv_layer_h<5,  2,  12, 1 >(bufA, bufB, s_edge, row_start, perm, wr4, br4, wq4, tid);
    __syncthreads();

    // row-major f16 store: H[g][396] (word = half2 of channels 2t, 2t+1)
    if (tid < NPG)
        ((unsigned*)H)[g * 198 + tid] = bufB[tid];
}

// ---------------------------------------------------------------------------
// MLP as fused MFMA GEMM chain. One block = 16 graphs (one 16-row M-tile).
// v_mfma_f32_16x16x16_f16 layouts: A row=l&15, k=(l>>4)*4+j; B col=l&15,
// same k; D col=l&15, row=(l>>4)*4+j.
// ---------------------------------------------------------------------------

__device__ __forceinline__ void zero_words(void* p, int nwords, int tid)
{
    unsigned* u = (unsigned*)p;
    for (int i = tid; i < nwords; i += 256) u[i] = 0u;
}

template<int KC, int NTT, int NOUT, int SIN, int SOUT>
__device__ __forceinline__ void mfma_layer(
    const _Float16* __restrict__ inb,    // LDS [16][SIN]
    _Float16* __restrict__ outb,         // LDS [16][SOUT] (pre-zeroed)
    const _Float16* __restrict__ wtb,    // global [KC][NTT*16][16]
    const float* __restrict__ bias, int tid)
{
    constexpr int NPAD = NTT * 16;
    const int lane = tid & 63, wid = tid >> 6;
    const int lrow = lane & 15, lgrp = lane >> 4;
    const _Float16* aptr = inb + lrow * SIN + lgrp * 4;

    for (int nt0 = wid; nt0 < NTT; nt0 += 8) {
        const int  nt1  = nt0 + 4;
        const bool has2 = nt1 < NTT;
        f32x4 acc0 = {0.f, 0.f, 0.f, 0.f};
        f32x4 acc1 = {0.f, 0.f, 0.f, 0.f};
        const int n0 = nt0 * 16 + lrow;
        const int n1 = nt1 * 16 + lrow;
        const _Float16* b0 = wtb + n0 * 16 + lgrp * 4;
        const _Float16* b1 = wtb + n1 * 16 + lgrp * 4;
#pragma unroll 4
        for (int kc = 0; kc < KC; ++kc) {
            const f16x4 a   = *(const f16x4*)(aptr + kc * 16);
            const f16x4 vb0 = *(const f16x4*)(b0 + (size_t)kc * (NPAD * 16));
            acc0 = __builtin_amdgcn_mfma_f32_16x16x16f16(a, vb0, acc0, 0, 0, 0);
            if (has2) {
                const f16x4 vb1 = *(const f16x4*)(b1 + (size_t)kc * (NPAD * 16));
                acc1 = __builtin_amdgcn_mfma_f32_16x16x16f16(a, vb1, acc1, 0, 0, 0);
            }
        }
        if (n0 < NOUT) {
            const float bv = bias[n0];
#pragma unroll
            for (int j = 0; j < 4; ++j)
                outb[(lgrp * 4 + j) * SOUT + n0] =
                    (_Float16)fmaxf(acc0[j] + bv, 0.f);
        }
        if (has2 && n1 < NOUT) {
            const float bv = bias[n1];
#pragma unroll
            for (int j = 0; j < 4; ++j)
                outb[(lgrp * 4 + j) * SOUT + n1] =
                    (_Float16)fmaxf(acc1[j] + bv, 0.f);
        }
    }
}

__global__ __launch_bounds__(256) void mlp_mfma_kernel(
    const _Float16* __restrict__ H,      // [NG][396] f16
    const _Float16* __restrict__ wtb,    // WTB base
    const float* __restrict__ lb0, const float* __restrict__ lb1,
    const float* __restrict__ lb2, const float* __restrict__ lb3,
    const float* __restrict__ lw4, const float* __restrict__ lb4,
    float* __restrict__ out)             // [NG, 2]
{
    __shared__ __align__(16) _Float16 bufH[16 * 400];  // 12.8 KB
    __shared__ __align__(16) _Float16 bufX[16 * 224];  // 7.2 KB
    __shared__ __align__(16) _Float16 bufY[16 * 128];  // 4.1 KB

    const int tid   = threadIdx.x;
    const int gbase = blockIdx.x * 16;

    // stage H tile (f16 word = 2 features) + zero K-pad cols + zero out bufs
    {
        const unsigned* Hw = (const unsigned*)H + (size_t)gbase * 198;
        unsigned* bH = (unsigned*)bufH;
        for (int t = tid; t < 16 * 200; t += 256) {
            const int gg = t / 200, w = t - gg * 200;
            bH[gg * 200 + w] = (w < 198) ? Hw[gg * 198 + w] : 0u;
        }
        zero_words(bufX, 16 * 224 / 2, tid);
        zero_words(bufY, 16 * 128 / 2, tid);
    }
    __syncthreads();

    // L0: [16x396] @ [396x200] -> bufX
    mfma_layer<25, 13, 200, 400, 224>(bufH, bufX, wtb, lb0, tid);
    __syncthreads();

    // L1: [16x200] @ [200x100] -> bufY ; concurrently zero bufH[0..1024) for L2
    zero_words(bufH, 512, tid);
    mfma_layer<13, 7, 100, 224, 128>(bufX, bufY, wtb + WTB1_OFF, lb1, tid);
    __syncthreads();

    // L2: [16x100] @ [100x50] -> bufH(stride 64) ; zero bufX[0..256) for L3
    zero_words(bufX, 128, tid);
    mfma_layer<7, 4, 50, 128, 64>(bufY, bufH, wtb + WTB2_OFF, lb2, tid);
    __syncthreads();

    // L3: [16x50] @ [50x10] -> bufX(stride 16)
    mfma_layer<4, 1, 10, 64, 16>(bufH, bufX, wtb + WTB3_OFF, lb3, tid);
    __syncthreads();

    // L4 (10 -> 2) + softmax, one thread per graph
    if (tid < 16) {
        float l0 = lb4[0], l1 = lb4[1];
#pragma unroll
        for (int k = 0; k < 10; ++k) {
            const float hv = (float)bufX[tid * 16 + k];
            l0 = fmaf(hv, lw4[k],      l0);
            l1 = fmaf(hv, lw4[10 + k], l1);
        }
        const float m  = fmaxf(l0, l1);
        const float e0 = __expf(l0 - m), e1 = __expf(l1 - m);
        const float inv = 1.f / (e0 + e1);
        float2 p; p.x = e0 * inv; p.y = e1 * inv;
        ((float2*)out)[gbase + tid] = p;
    }
}

extern "C" void kernel_launch(void* const* d_in, const int* in_sizes, int n_in,
                              void* d_out, int out_size, void* d_ws, size_t ws_size,
                              hipStream_t stream)
{
    const float* x    = (const float*)d_in[0];
    const int*   eidx = (const int*)  d_in[1];
    const float* ew   = (const float*)d_in[2];

    const float* wr[5]; const float* br[5]; const float* wq[5];
    for (int i = 0; i < 5; ++i) {
        wr[i] = (const float*)d_in[3 + 3 * i];
        br[i] = (const float*)d_in[4 + 3 * i];
        wq[i] = (const float*)d_in[5 + 3 * i];
    }
    const float* lw[5]; const float* lb[5];
    for (int i = 0; i < 5; ++i) {
        lw[i] = (const float*)d_in[18 + 2 * i];
        lb[i] = (const float*)d_in[19 + 2 * i];
    }

    _Float16* wsH = (_Float16*)d_ws;                  // H: [NG][396] f16
    _Float16* wtb = wsH + (size_t)H_F16S;             // packed MLP weights

    wtrans16_kernel<<<(WTB_TOTAL + 255) / 256, 256, 0, stream>>>(
        lw[0], lw[1], lw[2], lw[3], wtb);

    conv_kernel<<<NG, 256, 0, stream>>>(
        x, eidx, ew,
        wr[0], br[0], wq[0],
        wr[1], br[1], wq[1],
        wr[2], br[2], wq[2],
        wr[3], br[3], wq[3],
        wr[4], br[4], wq[4],
        wsH);

    mlp_mfma_kernel<<<NG / 16, 256, 0, stream>>>(
        wsH, wtb,
        lb[0], lb[1], lb[2], lb[3],
        lw[4], lb[4],
        (float*)d_out);
}